// Round 1
// baseline (524.044 us; speedup 1.0000x reference)
//
#include <hip/hip_runtime.h>
#include <hip/hip_bf16.h>

#define DF 128

typedef __attribute__((ext_vector_type(8))) short short8;   // 8 bf16 (4 VGPRs)
typedef __attribute__((ext_vector_type(4))) float floatx4;  // MFMA accumulator

__device__ __forceinline__ unsigned short f2bf(float f) {
  unsigned u = __float_as_uint(f);
  u += 0x7fffu + ((u >> 16) & 1u);   // round-to-nearest-even
  return (unsigned short)(u >> 16);
}

// ---------------- CSR build ----------------

__global__ void count_deg(const int* __restrict__ dst, int* __restrict__ deg, int e) {
  int i = blockIdx.x * 256 + threadIdx.x;
  if (i < e) atomicAdd(&deg[dst[i]], 1);
}

// exclusive block-scan; writes per-block totals to bsum (if non-null)
__global__ __launch_bounds__(1024) void scan_block(const int* __restrict__ in,
                                                   int* __restrict__ out,
                                                   int* __restrict__ bsum, int n) {
  __shared__ int wsum[16];
  int i = blockIdx.x * 1024 + threadIdx.x;
  int v = (i < n) ? in[i] : 0;
  int lane = threadIdx.x & 63;
  int wid = threadIdx.x >> 6;
  int s = v;
#pragma unroll
  for (int off = 1; off < 64; off <<= 1) {
    int t = __shfl_up(s, off);
    if (lane >= off) s += t;
  }
  if (lane == 63) wsum[wid] = s;
  __syncthreads();
  if (wid == 0) {
    int ws = (lane < 16) ? wsum[lane] : 0;
#pragma unroll
    for (int off = 1; off < 16; off <<= 1) {
      int t = __shfl_up(ws, off);
      if (lane >= off) ws += t;
    }
    if (lane < 16) wsum[lane] = ws;
  }
  __syncthreads();
  int wexcl = (wid > 0) ? wsum[wid - 1] : 0;
  int incl = s + wexcl;
  if (i < n) out[i] = incl - v;  // exclusive
  if (threadIdx.x == 1023 && bsum != nullptr) bsum[blockIdx.x] = incl;
}

__global__ __launch_bounds__(1024) void add_off(int* __restrict__ rs,
                                                const int* __restrict__ boff, int n) {
  int i = blockIdx.x * 1024 + threadIdx.x;
  if (i < n) rs[i] += boff[blockIdx.x];
}

// after this, rs[d] = inclusive scan (end offset); start(d) = rs[d-1] (0 for d==0)
__global__ void fill_csr(const int* __restrict__ src, const int* __restrict__ dst,
                         int* __restrict__ rs, int* __restrict__ csr, int e) {
  int i = blockIdx.x * 256 + threadIdx.x;
  if (i < e) {
    int d = dst[i];
    int p = atomicAdd(&rs[d], 1);
    csr[p] = src[i];
  }
}

// ---------------- dtype prep ----------------

__global__ void conv_x(const float* __restrict__ x, unsigned short* __restrict__ xb, int n4) {
  int i = blockIdx.x * 256 + threadIdx.x;
  if (i < n4) {
    float4 v = ((const float4*)x)[i];
    union { unsigned short u[4]; uint2 d; } o;
    o.u[0] = f2bf(v.x); o.u[1] = f2bf(v.y); o.u[2] = f2bf(v.z); o.u[3] = f2bf(v.w);
    ((uint2*)xb)[i] = o.d;
  }
}

// swizzle W[128][128] fp32 into MFMA-B fragment order (bf16):
// frag idx t = ((kt*8+nt)*64 + lane)*8 + j ; element = W[kt*32 + (lane>>4)*8 + j][nt*16 + (lane&15)]
__global__ void reorder_w(const float* __restrict__ W, unsigned short* __restrict__ wf) {
  int t = blockIdx.x * 256 + threadIdx.x;  // [0, 16384)
  int j = t & 7, lane = (t >> 3) & 63, ktnt = t >> 9;
  int nt = ktnt & 7, kt = ktnt >> 3;
  int k = kt * 32 + (lane >> 4) * 8 + j;
  int ncol = nt * 16 + (lane & 15);
  wf[t] = f2bf(W[k * DF + ncol]);
}

// ---------------- mean aggregation (one wave per node) ----------------
// feat: bf16 rows of 128 viewed as 64 uints (lane holds feats 2*lane, 2*lane+1)
__global__ __launch_bounds__(256) void aggregate(const unsigned int* __restrict__ feat,
                                                 const int* __restrict__ rs,
                                                 const int* __restrict__ csr,
                                                 unsigned int* __restrict__ out, int n) {
  int node = (blockIdx.x * 256 + threadIdx.x) >> 6;
  int lane = threadIdx.x & 63;
  if (node >= n) return;
  int s = (node > 0) ? rs[node - 1] : 0;
  int e = rs[node];
  float a0 = 0.f, a1 = 0.f;
  int i = s;
  for (; i + 3 < e; i += 4) {
    int i0 = csr[i], i1 = csr[i + 1], i2 = csr[i + 2], i3 = csr[i + 3];
    unsigned u0 = feat[i0 * 64 + lane];
    unsigned u1 = feat[i1 * 64 + lane];
    unsigned u2 = feat[i2 * 64 + lane];
    unsigned u3 = feat[i3 * 64 + lane];
    a0 += __uint_as_float(u0 << 16) + __uint_as_float(u1 << 16) +
          __uint_as_float(u2 << 16) + __uint_as_float(u3 << 16);
    a1 += __uint_as_float(u0 & 0xffff0000u) + __uint_as_float(u1 & 0xffff0000u) +
          __uint_as_float(u2 & 0xffff0000u) + __uint_as_float(u3 & 0xffff0000u);
  }
  for (; i < e; ++i) {
    unsigned u0 = feat[csr[i] * 64 + lane];
    a0 += __uint_as_float(u0 << 16);
    a1 += __uint_as_float(u0 & 0xffff0000u);
  }
  float sc = 1.0f / (float)max(e - s, 1);
  a0 *= sc; a1 *= sc;
  out[node * 64 + lane] = (unsigned)f2bf(a0) | ((unsigned)f2bf(a1) << 16);
}

// ---------------- fused SAGE linear: out = Aagg@Wl + Aself@Wr + b (opt relu) ----------------
// wave handles 32 rows x 128 cols, K=256 (two 128 sources), 128 MFMAs. No LDS.
__global__ __launch_bounds__(256) void gemm_sage(const unsigned short* __restrict__ Aagg,
                                                 const unsigned short* __restrict__ Aself,
                                                 const unsigned short* __restrict__ WFl,
                                                 const unsigned short* __restrict__ WFr,
                                                 const float* __restrict__ bias,
                                                 void* __restrict__ outp, int n,
                                                 int relu_out_bf16) {
  int wave = threadIdx.x >> 6;
  int lane = threadIdx.x & 63;
  int l16 = lane & 15, quad = lane >> 4;
  int rbase = (blockIdx.x * 4 + wave) * 32;
  if (rbase >= n) return;

  floatx4 acc[2][8];
#pragma unroll
  for (int a = 0; a < 2; ++a)
#pragma unroll
    for (int b = 0; b < 8; ++b) acc[a][b] = (floatx4)0.0f;

  int r0 = min(rbase + l16, n - 1);
  int r1 = min(rbase + 16 + l16, n - 1);

#pragma unroll
  for (int s = 0; s < 2; ++s) {
    const unsigned short* A = s ? Aself : Aagg;
    const unsigned short* W = s ? WFr : WFl;
#pragma unroll
    for (int kt = 0; kt < 4; ++kt) {
      short8 a0 = *(const short8*)(A + r0 * DF + kt * 32 + quad * 8);
      short8 a1 = *(const short8*)(A + r1 * DF + kt * 32 + quad * 8);
#pragma unroll
      for (int nt = 0; nt < 8; ++nt) {
        short8 bf = *(const short8*)(W + (((kt * 8 + nt) * 64) + lane) * 8);
        acc[0][nt] = __builtin_amdgcn_mfma_f32_16x16x32_bf16(a0, bf, acc[0][nt], 0, 0, 0);
        acc[1][nt] = __builtin_amdgcn_mfma_f32_16x16x32_bf16(a1, bf, acc[1][nt], 0, 0, 0);
      }
    }
  }

  float bv[8];
#pragma unroll
  for (int nt = 0; nt < 8; ++nt) bv[nt] = bias[nt * 16 + l16];

  // C/D mapping: col = lane&15, row = quad*4 + reg   [verified m89/m91]
  if (relu_out_bf16) {
    unsigned short* O = (unsigned short*)outp;
#pragma unroll
    for (int rb = 0; rb < 2; ++rb)
#pragma unroll
      for (int i = 0; i < 4; ++i) {
        int row = rbase + rb * 16 + quad * 4 + i;
        if (row < n) {
#pragma unroll
          for (int nt = 0; nt < 8; ++nt) {
            float v = acc[rb][nt][i] + bv[nt];
            O[row * DF + nt * 16 + l16] = f2bf(fmaxf(v, 0.0f));
          }
        }
      }
  } else {
    float* O = (float*)outp;
#pragma unroll
    for (int rb = 0; rb < 2; ++rb)
#pragma unroll
      for (int i = 0; i < 4; ++i) {
        int row = rbase + rb * 16 + quad * 4 + i;
        if (row < n) {
#pragma unroll
          for (int nt = 0; nt < 8; ++nt)
            O[row * DF + nt * 16 + l16] = acc[rb][nt][i] + bv[nt];
        }
      }
  }
}

// ---------------- launch ----------------

extern "C" void kernel_launch(void* const* d_in, const int* in_sizes, int n_in,
                              void* d_out, int out_size, void* d_ws, size_t ws_size,
                              hipStream_t stream) {
  const float* x   = (const float*)d_in[0];
  const int*   ei  = (const int*)d_in[1];
  const float* Wl1 = (const float*)d_in[2];
  const float* bl1 = (const float*)d_in[3];
  const float* Wr1 = (const float*)d_in[4];
  const float* Wl2 = (const float*)d_in[5];
  const float* bl2 = (const float*)d_in[6];
  const float* Wr2 = (const float*)d_in[7];

  int n = in_sizes[0] / DF;
  int e = in_sizes[1] / 2;
  const int* srcv = ei;
  const int* dstv = ei + e;

  char* ws = (char*)d_ws;
  size_t off = 0;
  auto alloc = [&](size_t bytes) {
    void* p = ws + off;
    off = (off + bytes + 255) & ~(size_t)255;
    return p;
  };
  int* deg  = (int*)alloc((size_t)n * 4);
  int* rs   = (int*)alloc((size_t)n * 4);
  int* bsum = (int*)alloc(4096);
  int* boff = (int*)alloc(4096);
  int* csr  = (int*)alloc((size_t)e * 4);
  unsigned short* xb   = (unsigned short*)alloc((size_t)n * DF * 2);
  unsigned short* hb   = (unsigned short*)alloc((size_t)n * DF * 2);
  unsigned short* aggb = (unsigned short*)alloc((size_t)n * DF * 2);
  unsigned short* wf   = (unsigned short*)alloc(4 * DF * DF * 2);
  unsigned short* wfl1 = wf;
  unsigned short* wfr1 = wf + 16384;
  unsigned short* wfl2 = wf + 32768;
  unsigned short* wfr2 = wf + 49152;

  hipMemsetAsync(deg, 0, (size_t)n * 4, stream);
  count_deg<<<(e + 255) / 256, 256, 0, stream>>>(dstv, deg, e);

  int nb = (n + 1023) / 1024;
  scan_block<<<nb, 1024, 0, stream>>>(deg, rs, bsum, n);
  scan_block<<<1, 1024, 0, stream>>>(bsum, boff, (int*)nullptr, nb);
  add_off<<<nb, 1024, 0, stream>>>(rs, boff, n);

  conv_x<<<((n * DF / 4) + 255) / 256, 256, 0, stream>>>(x, xb, n * DF / 4);
  reorder_w<<<64, 256, 0, stream>>>(Wl1, wfl1);
  reorder_w<<<64, 256, 0, stream>>>(Wr1, wfr1);
  reorder_w<<<64, 256, 0, stream>>>(Wl2, wfl2);
  reorder_w<<<64, 256, 0, stream>>>(Wr2, wfr2);

  fill_csr<<<(e + 255) / 256, 256, 0, stream>>>(srcv, dstv, rs, csr, e);

  aggregate<<<(n + 3) / 4, 256, 0, stream>>>((const unsigned int*)xb, rs, csr,
                                             (unsigned int*)aggb, n);
  gemm_sage<<<(n + 127) / 128, 256, 0, stream>>>(aggb, xb, wfl1, wfr1, bl1, hb, n, 1);
  aggregate<<<(n + 3) / 4, 256, 0, stream>>>((const unsigned int*)hb, rs, csr,
                                             (unsigned int*)aggb, n);
  gemm_sage<<<(n + 127) / 128, 256, 0, stream>>>(aggb, hb, wfl2, wfr2, bl2, d_out, n, 0);
}